// Round 6
// baseline (160.264 us; speedup 1.0000x reference)
//
#include <hip/hip_runtime.h>

// VectorQuantizer: N=65536 rows, D=256, K=1024 codes, fp32 in/out.
// argmin_k ||x-e_k||^2 == argmax_k (x.e_k - 0.5*||e_k||^2).
// R6 = R5 (512-thr blocks, 8 waves = 4 row-groups x 2 code-halves, GLDS
// double-buffered codebook tiles, counted-vmcnt double-barrier pipeline,
// setprio around MFMA) + two critical-path cuts:
//  (1) deferred top3 (accA/accB 2-chunk unroll): chunk c's top3 VALU runs
//      interleaved with chunk c+1's independent MFMA chain, off the
//      critical path (R3 feature that R5 dropped);
//  (2) float-domain top3: code embedded in the 10 low mantissa bits
//      ((bits & 0xFFFFFC00)|code is IEEE-compare monotonic); insert =
//      v_max_f32 + 2x v_med3_f32 = 3 ops, pack = 2 ops -> ~5 VALU/score
//      vs ~11 for the old u32-sortable scheme. Embedding perturbs scores
//      by <= |s|*2^-13 ~ 0.012, inside the 0.25 exact-fp32 rescue margin;
//      exact ties -> margin 0 -> rescued -> lowest-index tie-break kept.
// R4 lesson kept: codebook must stream through LDS (global->VGPR needs
// 512 B/cyc/CU; L1 path delivers ~64).

#define K_EMB  1024
#define D_DIM  256
#define N_ROWS 65536

typedef unsigned int u32;
typedef unsigned long long u64;
typedef __attribute__((ext_vector_type(8)))  _Float16 f16x8;
typedef __attribute__((ext_vector_type(4)))  _Float16 f16x4;
typedef __attribute__((ext_vector_type(16))) float    f32x16;

#define GLDS(gp, lp) __builtin_amdgcn_global_load_lds( \
    (const __attribute__((address_space(1))) void*)(gp), \
    (__attribute__((address_space(3))) void*)(lp), 16, 0, 0)

// ---- prep: emb fp32 -> fp16 (linear [code][dim]); cn2c[code] = packed
// ---- {-cnh,-cnl} fp16 pair (u32); exact fp32 cnorm ----
__global__ void vq_prep(const float* __restrict__ emb,
                        _Float16* __restrict__ ehi,
                        u32* __restrict__ cn2c,
                        float* __restrict__ cnormf) {
    int gid = blockIdx.x * 256 + threadIdx.x;
    int code = gid >> 6, lane = gid & 63;
    float4 v = ((const float4*)(emb + (size_t)code * D_DIM))[lane];
    f16x4 hv = {(_Float16)v.x, (_Float16)v.y, (_Float16)v.z, (_Float16)v.w};
    ((f16x4*)(ehi + (size_t)code * D_DIM))[lane] = hv;
    float s = v.x * v.x + v.y * v.y + v.z * v.z + v.w * v.w;
    #pragma unroll
    for (int off = 32; off > 0; off >>= 1) s += __shfl_down(s, off, 64);
    if (lane == 0) {
        float cn = 0.5f * s;
        cnormf[code] = cn;
        _Float16 ch = (_Float16)cn;
        _Float16 cl = (_Float16)(cn - (float)ch);
        union { _Float16 hh[2]; u32 uu; } pk;
        pk.hh[0] = (_Float16)(-(float)ch);
        pk.hh[1] = (_Float16)(-(float)cl);
        cn2c[code] = pk.uu;
    }
}

// ---- fused main: GEMM + deferred top3 + merge + rescue + gather ----
__global__ __launch_bounds__(512, 4) void vq_main(
    const float* __restrict__ x, const float* __restrict__ emb,
    const _Float16* __restrict__ eh, const u32* __restrict__ cn2c,
    const float* __restrict__ cnormf,
    float* __restrict__ outq, float* __restrict__ outi)
{
    // T[parity][code-half][s 0..15][kh][code 0..31][8 halfs]: 2 x 32 KB
    __shared__ _Float16 T[2][2][8192];
    __shared__ u32 CNs[1024];         // packed {-cnh,-cnl} per code, 4 KB
    __shared__ u32 xchg[2][128][3];   // [code-half][local row][rank]
    __shared__ int winners[128];

    const int t = threadIdx.x, w = t >> 6, lane = t & 63;
    const int m = lane & 31, kh = lane >> 5;
    const int p = w >> 1;                 // row-group 0..3 (32 rows each)
    const int h = w & 1;                  // code half: codes h*512..+512
    const int blkrow = blockIdx.x * 128;
    const int kh4 = kh * 4;
    const float NEGINF = __uint_as_float(0xFF800000u);

    // stage chunk c (32 codes per half) into T[c&1]; wave w covers half h,
    // dim-regions r = p*4 + [0..4)  -> exactly 4 GLDS per wave per chunk.
    auto stage = [&](int c) {
        _Float16* dstb = &T[c & 1][h][0];
        const _Float16* srcb = eh + (size_t)(h * 512 + c * 32 + m) * D_DIM + kh * 8;
        #pragma unroll
        for (int i = 0; i < 4; i++) {
            int r = p * 4 + i;
            GLDS(srcb + r * 16, dstb + r * 512);
        }
    };

    stage(0);   // first codebook tile in flight during the x prologue

    // cnorm pairs -> LDS (one-time; visible after first __syncthreads)
    CNs[t] = cn2c[t];
    CNs[t + 512] = cn2c[t + 512];

    // ---- coalesced x prologue through T[1] (two 64-row passes) ----
    // write: [row][dim] fp16, 512 B/row, byte ^= (row&7)<<4 swizzle.
    // read:  lane(m,kh) frag s = halfs [lr][s*16+kh*8..+8) -> ds_read_b128.
    f16x8 bh[16];
    {
        char* xb = (char*)&T[1][0][0];    // 32 KB staging region
        #pragma unroll
        for (int k = 0; k < 2; k++) {
            #pragma unroll
            for (int i = 0; i < 8; i++) {
                int row = i * 8 + w;       // 0..63, whole row per wave-instr
                float4 v = *(const float4*)(
                    x + (size_t)(blkrow + k * 64 + row) * D_DIM + lane * 4);
                f16x4 hv = {(_Float16)v.x, (_Float16)v.y,
                            (_Float16)v.z, (_Float16)v.w};
                u32 byte = (u32)(row * 512 + lane * 8) ^ ((u32)(row & 7) << 4);
                *(f16x4*)(xb + byte) = hv;
            }
            __syncthreads();
            if ((p >> 1) == k) {
                int lr = (p & 1) * 32 + m;
                #pragma unroll
                for (int s = 0; s < 16; s++) {
                    u32 byte = (u32)(lr * 512 + s * 32 + kh * 16)
                             ^ ((u32)(lr & 7) << 4);
                    bh[s] = *(const f16x8*)(xb + byte);
                }
            }
            __syncthreads();
        }
    }
    f16x8 xe = {};
    if (kh == 0) { xe[0] = (_Float16)1.0f; xe[1] = (_Float16)1.0f; }

    // float-domain top3 state (code in 10 low mantissa bits)
    float B1 = NEGINF, B2 = NEGINF, B3 = NEGINF;

    auto t3f = [](float& c1, float& c2, float& c3, float pv) {
        float n3 = __builtin_amdgcn_fmed3f(c2, pv, c3);
        float n2 = __builtin_amdgcn_fmed3f(c1, pv, c2);
        c1 = fmaxf(c1, pv);
        c2 = n2; c3 = n3;
    };

    // 17 MFMAs of chunk c into acc (independent chain per acc)
    auto computeMF = [&](int buf, f32x16& a, int c) {
        const f16x8* Af = (const f16x8*)&T[buf][h][0];
        union { u32 uu; _Float16 hh[2]; } uv;
        uv.uu = CNs[h * 512 + c * 32 + m];
        f16x8 e = {};
        e[0] = uv.hh[0]; e[1] = uv.hh[1];
        a = (f32x16){};
        __builtin_amdgcn_s_setprio(1);
        #pragma unroll
        for (int s = 0; s < 16; s++) {
            f16x8 fa = Af[(2 * s + kh) * 32 + m];
            a = __builtin_amdgcn_mfma_f32_32x32x16_f16(fa, bh[s], a, 0, 0, 0);
        }
        a = __builtin_amdgcn_mfma_f32_32x32x16_f16(e, xe, a, 0, 0, 0);
        __builtin_amdgcn_s_setprio(0);
    };

    auto top3p = [&](const f32x16& a, int c) {
        const u32 sbase = (u32)(h * 512 + c * 32) + kh4;
        #pragma unroll
        for (int r = 0; r < 16; r++) {
            u32 code = sbase + (r & 3) + 8 * (r >> 2);
            u32 bits = (__float_as_uint(a[r]) & 0xFFFFFC00u) | code;
            t3f(B1, B2, B3, __uint_as_float(bits));
        }
    };

    // ---- main loop: 16 chunks, counted-vmcnt pipeline, deferred top3 ----
    // iter: [SB; s_barrier]  WAR: all waves done reading the buffer the
    //       next stage overwrites; stage; vmcnt(4): previous tile landed,
    //       new 4 loads in flight; [SB; s_barrier]  RAW: tile visible.
    //       compute chunk c; top3 of chunk c-1 fills c's MFMA shadow.
    f32x16 accA, accB;
    for (int cc = 0; cc < 16; cc += 2) {
        __builtin_amdgcn_sched_barrier(0);
        __builtin_amdgcn_s_barrier();
        stage(cc + 1);
        asm volatile("s_waitcnt vmcnt(4)" ::: "memory");
        __builtin_amdgcn_sched_barrier(0);
        __builtin_amdgcn_s_barrier();
        computeMF(0, accA, cc);
        if (cc) top3p(accB, cc - 1);

        __builtin_amdgcn_sched_barrier(0);
        __builtin_amdgcn_s_barrier();
        if (cc + 2 < 16) {
            stage(cc + 2);
            asm volatile("s_waitcnt vmcnt(4)" ::: "memory");
        } else {
            asm volatile("s_waitcnt vmcnt(0)" ::: "memory");
        }
        __builtin_amdgcn_sched_barrier(0);
        __builtin_amdgcn_s_barrier();
        computeMF(1, accB, cc + 1);
        top3p(accA, cc);
    }
    top3p(accB, 15);

    // merge the two kh-halves of each row (partner lane = lane ^ 32)
    {
        float q1 = __shfl_xor(B1, 32, 64);
        float q2 = __shfl_xor(B2, 32, 64);
        float q3 = __shfl_xor(B3, 32, 64);
        t3f(B1, B2, B3, q1); t3f(B1, B2, B3, q2); t3f(B1, B2, B3, q3);
    }

    // cross-wave (code-half) exchange of per-row top3
    if (kh == 0) {
        int ra = p * 32 + m;
        xchg[h][ra][0] = __float_as_uint(B1);
        xchg[h][ra][1] = __float_as_uint(B2);
        xchg[h][ra][2] = __float_as_uint(B3);
    }
    __syncthreads();

    // epilogue: each wave owns 16 rows (local rows w*16 .. w*16+16)
    const int lr = w * 16 + (lane & 15);
    float c1 = NEGINF, c2 = NEGINF, c3 = NEGINF;
    #pragma unroll
    for (int hh = 0; hh < 2; hh++) {
        t3f(c1, c2, c3, __uint_as_float(xchg[hh][lr][0]));
        t3f(c1, c2, c3, __uint_as_float(xchg[hh][lr][1]));
        t3f(c1, c2, c3, __uint_as_float(xchg[hh][lr][2]));
    }

    // rescue selection: exact fp32 re-eval when approx margin <= 0.25
    u32 i1 = __float_as_uint(c1) & 1023u;
    u32 i2 = __float_as_uint(c2) & 1023u;
    u32 i3 = __float_as_uint(c3) & 1023u;
    const bool act = lane < 16;
    bool need = (c1 - c2) <= 0.25f;
    if (act && !need) winners[lr] = (int)i1;
    u64 mask = __ballot(act && need);
    while (mask) {
        int r = __ffsll((unsigned long long)mask) - 1;
        mask &= mask - 1;
        int row = blkrow + w * 16 + r;
        u32 d1 = (u32)__shfl((int)i1, r, 64);
        u32 d2 = (u32)__shfl((int)i2, r, 64);
        u32 d3 = (u32)__shfl((int)i3, r, 64);
        float g3 = __shfl(c1 - c3, r, 64);
        int ncand = (g3 <= 0.25f) ? 3 : 2;
        float4 xv = ((const float4*)(x + (size_t)row * D_DIM))[lane];
        float bs = -3.0e38f; int bi = 0x7fffffff;
        u32 cand[3] = {d1, d2, d3};
        for (int q = 0; q < ncand; q++) {
            int ccd = (int)cand[q];
            float4 ev = ((const float4*)(emb + (size_t)ccd * D_DIM))[lane];
            float d = xv.x * ev.x + xv.y * ev.y + xv.z * ev.z + xv.w * ev.w;
            #pragma unroll
            for (int dd = 1; dd < 64; dd <<= 1) d += __shfl_xor(d, dd, 64);
            float sc = d - cnormf[ccd];
            if (sc > bs || (sc == bs && ccd < bi)) { bs = sc; bi = ccd; }
        }
        if (lane == 0) winners[w * 16 + r] = bi;
    }

    // index write + gather (winners slots are wave-private; no barrier needed)
    if (act) outi[blkrow + lr] = (float)winners[lr];
    #pragma unroll 8
    for (int r = 0; r < 16; r++) {
        int idx = winners[w * 16 + r];
        int row = blkrow + w * 16 + r;
        float4 qv = ((const float4*)(emb + (size_t)idx * D_DIM))[lane];
        ((float4*)(outq + (size_t)row * D_DIM))[lane] = qv;
    }
}

extern "C" void kernel_launch(void* const* d_in, const int* in_sizes, int n_in,
                              void* d_out, int out_size, void* d_ws, size_t ws_size,
                              hipStream_t stream) {
    const float* x   = (const float*)d_in[0];
    const float* emb = (const float*)d_in[1];
    float* outq = (float*)d_out;
    float* outi = outq + (size_t)N_ROWS * D_DIM;

    _Float16* ehi = (_Float16*)d_ws;                              // 512 KB
    u32* cn2c = (u32*)(ehi + (size_t)K_EMB * D_DIM);              // 4 KB
    float* cnormf = (float*)(cn2c + K_EMB);                       // 4 KB

    vq_prep<<<K_EMB / 4, 256, 0, stream>>>(emb, ehi, cn2c, cnormf);
    vq_main<<<N_ROWS / 128, 512, 0, stream>>>(x, emb, ehi, cn2c, cnormf,
                                              outq, outi);
}